// Round 7
// baseline (188.331 us; speedup 1.0000x reference)
//
#include <hip/hip_runtime.h>

// GraphAugmentation fused kernel, MI355X — R7.
//
// Algebra:
//  * softmax over 8 identical affinities == 1/8 -> Q/K/attn dead.
//  * u = [xc ; xavg] (K=32), xavg = mean of 8 rolls of x.
//  * agg    = [0|mw] @ u + mb                                  (16x32)
//  * hidden = relu(W1' @ u + b1'), W1' = [g1w_x | g1w_a@mw],
//             b1' = g1b + g1w_a@mb                             (32x32)
//  * gate   = sigmoid(g2w @ hidden + g2b)                      (16x32)
//  * out    = agg * gate
//
// R7 vs R6 (94us, latency-bound, 3.67M LDS conflicts, shfl chain, VGPR=72):
//  * W1' ROW PERMUTATION: aH0 row m <- W1' row 8(m>>2)+(m&3), aH1 <- +4.
//    Hidden MFMA D-registers then ARE the gate B-fragment (lane(q,m):
//    acc_h0[rg]=h-ch 8q+rg -> slot rg, acc_h1[rg]=h-ch 8q+4+rg -> slot
//    4+rg). No shfl, no LDS round-trip, no selects. Numerically identical.
//  * u staging padded to stride 40 halfs (80B): b128 write starts
//    (20*lane+4j)%32 and read starts (20m+4q)%32 cover all 8 16B slots
//    uniformly -> conflict-free, no XOR swizzle.
//  * __launch_bounds__(256,2): allow up to 256 VGPR so gather loads stay
//    in flight and the 4 groups' MFMA chains interleave.

#define HW 262144   // 512*512

typedef _Float16 half8  __attribute__((ext_vector_type(8)));
typedef float    f32x4  __attribute__((ext_vector_type(4)));

#define MFMA16(A, B, C) __builtin_amdgcn_mfma_f32_16x16x32_f16((A), (B), (C), 0, 0, 0)

__global__ __launch_bounds__(256, 2) void ga_main(
    const float* __restrict__ x,
    const float* __restrict__ mw,  const float* __restrict__ mb,
    const float* __restrict__ g1w, const float* __restrict__ g1b,
    const float* __restrict__ g2w, const float* __restrict__ g2b,
    float* __restrict__ out)
{
  constexpr int DY[8] = {-4, -4, -4, -3, -2, 2, 3, 4};
  constexpr int DX[8] = {-4, -1,  2,  4, -3, 3, -2, 4};

  __shared__ _Float16 u_s[4 * 64 * 40];  // 20 KB, stride 40 halfs (80 B): conflict-free
  __shared__ float    w1a[32 * 16];      //  2 KB: W1' columns k>=16
  __shared__ float    b1s[32];           // b1' = g1b + g1w_a @ mb

  const int tid  = threadIdx.x;
  const int wv   = tid >> 6, lane = tid & 63;
  const int q    = lane >> 4, m = lane & 15;

  // ---- block-cooperative prep: W1'a[j][c] and b1'[j] into LDS ----
  for (int idx = tid; idx < 512; idx += 256) {
    const int j = idx >> 4, c = idx & 15;
    float s = 0.f;
#pragma unroll
    for (int t2 = 0; t2 < 16; ++t2)
      s += g1w[j * 32 + 16 + t2] * mw[t2 * 16 + c];
    w1a[idx] = s;
  }
  if (tid < 32) {
    float s = g1b[tid];
#pragma unroll
    for (int t2 = 0; t2 < 16; ++t2)
      s += g1w[tid * 32 + 16 + t2] * mb[t2];
    b1s[tid] = s;
  }
  __syncthreads();

  // ---- per-lane weight A-fragments (fp16 hi+lo), element e <-> k=8q+e ----
  // Hidden rows PERMUTED so D-layout == gate B-layout:
  const int j0 = 8 * (m >> 2) + (m & 3);   // aH0 row m <- W1' row j0
  const int j1 = j0 + 4;                   // aH1 row m <- W1' row j1
  half8 aAg_h, aAg_l, aH0_h, aH0_l, aH1_h, aH1_l, aG2_h, aG2_l;
#pragma unroll
  for (int e = 0; e < 8; ++e) {
    const int kk = 8 * q + e;
    float v0 = 0.f;
    if (kk >= 16) v0 = mw[m * 16 + (kk - 16)];      // Abar = [0 | mw]
    _Float16 h = (_Float16)v0;
    aAg_h[e] = h; aAg_l[e] = (_Float16)(v0 - (float)h);

    float v1, v2;
    if (kk < 16) { v1 = g1w[j0 * 32 + kk];        v2 = g1w[j1 * 32 + kk]; }
    else         { v1 = w1a[j0 * 16 + (kk - 16)]; v2 = w1a[j1 * 16 + (kk - 16)]; }
    h = (_Float16)v1; aH0_h[e] = h; aH0_l[e] = (_Float16)(v1 - (float)h);
    h = (_Float16)v2; aH1_h[e] = h; aH1_l[e] = (_Float16)(v2 - (float)h);

    const float v3 = g2w[m * 32 + kk];              // unchanged (original ch idx)
    h = (_Float16)v3; aG2_h[e] = h; aG2_l[e] = (_Float16)(v3 - (float)h);
  }
  f32x4 bias0, bias1, bias2, bias3;
#pragma unroll
  for (int rg = 0; rg < 4; ++rg) {
    bias0[rg] = mb[4 * q + rg];
    bias1[rg] = b1s[8 * q + rg];        // acc_h0 reg rg = h-ch 8q+rg
    bias2[rg] = b1s[8 * q + 4 + rg];    // acc_h1 reg rg = h-ch 8q+4+rg
    bias3[rg] = g2b[4 * q + rg];
  }

  // ---- XCD-aware bijective swizzle (proven: FETCH 207->34 MB) ----
  const int swz = ((blockIdx.x & 7) << 9) | (blockIdx.x >> 3);
  const int b   = swz >> 10;
  const int rem = swz & 1023;
  const int row = rem >> 1;
  const int colbase = ((rem & 1) << 8) + wv * 64;
  const int cw  = colbase + lane;

  const float* xb = x + b * 16 * HW;
  unsigned off[8];
#pragma unroll
  for (int i = 0; i < 8; ++i)
    off[i] = ((row - DY[i]) & 511) * 512 + ((cw - DX[i]) & 511);
  const unsigned ctr = row * 512 + cw;

  // ---- gathers: xc (center), xa (mean of 8 rolls) ----
  float xc[16], xa[16];
#pragma unroll
  for (int c = 0; c < 16; ++c) {
    const float* xp = xb + c * HW;
    xc[c] = xp[ctr];
    float s = 0.f;
#pragma unroll
    for (int i = 0; i < 8; ++i) s += xp[off[i]];
    xa[c] = s * 0.125f;
  }

  // ---- pack u=[xc;xa] to fp16; stage at stride-40 (conflict-free b128) ----
  _Float16* ub = u_s + (wv * 64 + lane) * 40;
#pragma unroll
  for (int j = 0; j < 4; ++j) {
    half8 v;
#pragma unroll
    for (int e = 0; e < 8; ++e) {
      const int k = j * 8 + e;
      v[e] = (_Float16)((k < 16) ? xc[k] : xa[k - 16]);
    }
    *(half8*)(ub + j * 8) = v;
  }

  // ---- prefetch all 4 u B-fragments (conflict-free reads) ----
  const _Float16* ubase = u_s + wv * 64 * 40;
  half8 bf[4];
#pragma unroll
  for (int g = 0; g < 4; ++g)
    bf[g] = *(const half8*)(ubase + (g * 16 + m) * 40 + q * 8);

  float* ob = out + b * 16 * HW + row * 512 + colbase;
  const f32x4 z = {0.f, 0.f, 0.f, 0.f};

#pragma unroll
  for (int g = 0; g < 4; ++g) {
    // agg / hidden GEMMs: (Ahi+Alo) @ B, B single fp16
    f32x4 acc_a  = MFMA16(aAg_l, bf[g], z);
    acc_a        = MFMA16(aAg_h, bf[g], acc_a);
    f32x4 acc_h0 = MFMA16(aH0_l, bf[g], z);
    acc_h0       = MFMA16(aH0_h, bf[g], acc_h0);
    f32x4 acc_h1 = MFMA16(aH1_l, bf[g], z);
    acc_h1       = MFMA16(aH1_h, bf[g], acc_h1);

    // relu + fp16 pack: registers ARE the gate B-fragment (row-permuted W1')
    half8 gB;
#pragma unroll
    for (int rg = 0; rg < 4; ++rg) {
      gB[rg]     = (_Float16)fmaxf(acc_h0[rg] + bias1[rg], 0.f);
      gB[4 + rg] = (_Float16)fmaxf(acc_h1[rg] + bias2[rg], 0.f);
    }

    f32x4 acc_g = MFMA16(aG2_l, gB, z);
    acc_g       = MFMA16(aG2_h, gB, acc_g);

    // epilogue: out = (agg+mb) * sigmoid(gate_pre + g2b)
#pragma unroll
    for (int rg = 0; rg < 4; ++rg) {
      const float ag = acc_a[rg] + bias0[rg];
      const float gp = acc_g[rg] + bias3[rg];
      const float gt = __builtin_amdgcn_rcpf(1.f + __expf(-gp));
      ob[(4 * q + rg) * HW + g * 16 + m] = ag * gt;
    }
  }
}

extern "C" void kernel_launch(void* const* d_in, const int* in_sizes, int n_in,
                              void* d_out, int out_size, void* d_ws, size_t ws_size,
                              hipStream_t stream) {
  // setup_inputs() order:
  // 0:x 1:qw 2:qb 3:kw 4:kb 5:mw 6:mb 7:scaling 8:g1w 9:g1b 10:g2w 11:g2b
  const float* x   = (const float*)d_in[0];
  const float* mw  = (const float*)d_in[5];
  const float* mb  = (const float*)d_in[6];
  const float* g1w = (const float*)d_in[8];
  const float* g1b = (const float*)d_in[9];
  const float* g2w = (const float*)d_in[10];
  const float* g2b = (const float*)d_in[11];
  float* out = (float*)d_out;

  // 4096 wgs x 256 thr; wave = 64 px of one image row.
  ga_main<<<4096, 256, 0, stream>>>(x, mw, mb, g1w, g1b, g2w, g2b, out);
}